// Round 16
// baseline (199.388 us; speedup 1.0000x reference)
//
#include <hip/hip_runtime.h>

// GraphTransformerBlock2: GATConv(H=3,C=64, edge_dim=5, self-loops w/ mean fill)
// -> linear1 -> LN(x + .) -> linear2 -> LN(lin + .)
// All float32 I/O. edge_index int32 (2,E): src=ei[0:E], dst=ei[E:2E].
//
// R15: gather phase processes nodes in PAIRS (2 serial pair-iterations/wave
//      instead of 4 serial nodes): both payload loads issued together, phase B
//      interleaves one edge of each node per iteration (4 independent gather
//      loads in flight from 2 dependency chains), epilogues overlap.
//      Chunk=64 edges -> pair max-degree imbalance negligible at mean deg 16
//      (R13's failure was 16-edge chunks). wbuf 4->8 rows (LDS 17.4KB, still
//      not the occupancy limiter).

#define HH 3
#define CC 64
#define DIN 64
#define ED 5
#define HC 192
#define OAP 200                 // padded OA row stride (u16)
#define NEG_SLOPE 0.2f
#define LN_EPS 1e-5f
#define LOG2E 1.44269504f

typedef __attribute__((ext_vector_type(8))) short bf16x8;
typedef __attribute__((ext_vector_type(4))) float f32x4;

__device__ __forceinline__ float leaky(float l) { return fmaxf(l, NEG_SLOPE * l); }

__device__ __forceinline__ unsigned short f2bf(float f) {
    unsigned u = __float_as_uint(f);
    unsigned r = (u + 0x7FFFu + ((u >> 16) & 1u)) >> 16;   // RNE
    return (unsigned short)r;
}
__device__ __forceinline__ float bf2f(unsigned short u) {
    return __uint_as_float((unsigned)u << 16);
}
__device__ __forceinline__ float bf_lo(unsigned v) { return __uint_as_float(v << 16); }
__device__ __forceinline__ float bf_hi(unsigned v) { return __uint_as_float(v & 0xFFFF0000u); }

__device__ __forceinline__ bf16x8 pack8(float4 a, float4 b) {
    bf16x8 r;
    r[0] = (short)f2bf(a.x); r[1] = (short)f2bf(a.y);
    r[2] = (short)f2bf(a.z); r[3] = (short)f2bf(a.w);
    r[4] = (short)f2bf(b.x); r[5] = (short)f2bf(b.y);
    r[6] = (short)f2bf(b.z); r[7] = (short)f2bf(b.w);
    return r;
}

// ---------- prep: transposes (blocks 0..27), b1p+we (block 28), cnt (rest) ----------
#define PREP_TRANS (HC*DIN + DIN*HC + CC*CC)
#define PREP_BLOCKS 28
__global__ __launch_bounds__(256) void k_prep_cnt(const float* __restrict__ lin_w,
                                                  const float* __restrict__ w1,
                                                  const float* __restrict__ w2,
                                                  const float* __restrict__ b1,
                                                  const float* __restrict__ gat_bias,
                                                  const float* __restrict__ lin_edge_w,
                                                  const float* __restrict__ att_edge,
                                                  unsigned short* __restrict__ linwt,
                                                  unsigned short* __restrict__ w1t,
                                                  unsigned short* __restrict__ w2t,
                                                  float* __restrict__ b1p,
                                                  float* __restrict__ we,
                                                  const int* __restrict__ ei,
                                                  int* __restrict__ icnt, int E) {
    if (blockIdx.x < PREP_BLOCKS) {
        for (int i = blockIdx.x * 256 + threadIdx.x; i < PREP_TRANS; i += PREP_BLOCKS * 256) {
            if (i < HC * DIN) {
                int c = i >> 6, k = i & 63;
                linwt[i] = f2bf(lin_w[k * HC + c]);
            } else if (i < 2 * HC * DIN) {
                int j = i - HC * DIN;
                int c = j / HC, k = j - c * HC;
                w1t[j] = f2bf(w1[k * CC + c]);
            } else {
                int j = i - 2 * HC * DIN;
                int c = j >> 6, k = j & 63;
                w2t[j] = f2bf(w2[k * CC + c]);
            }
        }
    } else if (blockIdx.x == PREP_BLOCKS) {
        __shared__ float pb[4][CC];
        __shared__ float pw[15][16];
        int t = threadIdx.x;
        int c = t & 63, kq = t >> 6;
        float s = 0.f;
        for (int k = kq * 48; k < kq * 48 + 48; ++k)
            s += gat_bias[k] * w1[k * CC + c];
        pb[kq][c] = s;
        int q = t >> 4, cq = t & 15;
        if (q < 15) {
            int d = q / HH, h = q - d * HH;
            float s2 = 0.f;
            #pragma unroll
            for (int c2 = cq * 4; c2 < cq * 4 + 4; ++c2)
                s2 += lin_edge_w[d * HC + h * CC + c2] * att_edge[h * CC + c2];
            pw[q][cq] = s2;
        }
        __syncthreads();
        if (t < CC) b1p[t] = b1[t] + pb[0][t] + pb[1][t] + pb[2][t] + pb[3][t];
        if (t < 15) {
            float tot = 0.f;
            #pragma unroll
            for (int i2 = 0; i2 < 16; ++i2) tot += pw[t][i2];
            we[t] = tot * LOG2E;
        }
    } else {
        int nb = gridDim.x - PREP_BLOCKS - 1;
        for (int e = (blockIdx.x - PREP_BLOCKS - 1) * 256 + threadIdx.x; e < E; e += nb * 256)
            atomicAdd(&icnt[ei[E + e]], 1);
    }
}

// ---------- xs = x @ lin_w (MFMA) -> packed xsb + a_src/a_dst;  scan fused ----------
__global__ __launch_bounds__(256) void k_xs(const float* __restrict__ x,
                                            const unsigned short* __restrict__ linwt,
                                            const float* __restrict__ att_src,
                                            const float* __restrict__ att_dst,
                                            unsigned short* __restrict__ xsb,
                                            float* __restrict__ a_src,
                                            float* __restrict__ a_dst,
                                            const int* __restrict__ icnt,
                                            int* __restrict__ gtot,
                                            int* __restrict__ off,
                                            int* __restrict__ cursor,
                                            int N, int nbx) {
    __shared__ int wt[4];
    __shared__ int base_sh;
    if ((int)blockIdx.x >= nbx) {
        int bid = blockIdx.x - nbx;
        int i = bid * 256 + threadIdx.x;
        int lane = threadIdx.x & 63, wid = threadIdx.x >> 6;
        int v = (i < N) ? icnt[i] : 0;
        int incl = v;
        #pragma unroll
        for (int o = 1; o < 64; o <<= 1) {
            int u = __shfl_up(incl, o, 64);
            if (lane >= o) incl += u;
        }
        if (lane == 63) wt[wid] = incl;
        __syncthreads();
        if (threadIdx.x == 0)
            base_sh = atomicAdd(gtot, wt[0] + wt[1] + wt[2] + wt[3]);
        __syncthreads();
        int wpre = 0;
        for (int w2 = 0; w2 < wid; ++w2) wpre += wt[w2];
        int excl = base_sh + wpre + incl - v;
        if (i < N) { off[i] = excl; cursor[i] = excl; }
        return;
    }

    int lane = threadIdx.x & 63, w = threadIdx.x >> 6;
    int l15 = lane & 15, kg = (lane >> 4) * 8;
    int nb = blockIdx.x * 64;
    int arow = nb + w * 16 + l15;
    int arow_c = min(arow, N - 1);

    f32x4 acc[12];
    #pragma unroll
    for (int ct = 0; ct < 12; ++ct) acc[ct] = (f32x4){0.f, 0.f, 0.f, 0.f};

    #pragma unroll
    for (int k0 = 0; k0 < DIN; k0 += 32) {
        const float* ap = x + (size_t)arow_c * DIN + k0 + kg;
        float4 a0 = *(const float4*)ap;
        float4 a1 = *(const float4*)(ap + 4);
        bf16x8 af = pack8(a0, a1);
        #pragma unroll
        for (int ct = 0; ct < 12; ++ct) {
            bf16x8 bf = *(const bf16x8*)(linwt + (size_t)(ct * 16 + l15) * DIN + k0 + kg);
            acc[ct] = __builtin_amdgcn_mfma_f32_16x16x32_bf16(af, bf, acc[ct], 0, 0, 0);
        }
    }

    float asv[12], adv[12];
    #pragma unroll
    for (int ct = 0; ct < 12; ++ct) {
        int c = ct * 16 + l15;
        asv[ct] = att_src[c]; adv[ct] = att_dst[c];
    }

    int rbase = nb + w * 16 + (lane >> 4) * 4;
    #pragma unroll
    for (int j = 0; j < 4; ++j) {
        int r = rbase + j;
        bool ok = r < N;
        float ps0 = 0.f, ps1 = 0.f, ps2 = 0.f, pd0 = 0.f, pd1 = 0.f, pd2 = 0.f;
        #pragma unroll
        for (int ct = 0; ct < 12; ++ct) {
            float v = acc[ct][j];
            float s = v * asv[ct], d = v * adv[ct];
            if (ct < 4)      { ps0 += s; pd0 += d; }
            else if (ct < 8) { ps1 += s; pd1 += d; }
            else             { ps2 += s; pd2 += d; }
        }
        if (ok) {
            unsigned* row32 = (unsigned*)(xsb + (size_t)r * HC);
            #pragma unroll
            for (int ct = 0; ct < 4; ++ct) {
                int c = ct * 16 + l15;
                row32[c] = (unsigned)f2bf(acc[ct][j]) | ((unsigned)f2bf(acc[ct + 4][j]) << 16);
                xsb[(size_t)r * HC + 128 + c] = f2bf(acc[ct + 8][j]);
            }
        }
        #pragma unroll
        for (int o = 1; o < 16; o <<= 1) {
            ps0 += __shfl_xor(ps0, o, 64); pd0 += __shfl_xor(pd0, o, 64);
            ps1 += __shfl_xor(ps1, o, 64); pd1 += __shfl_xor(pd1, o, 64);
            ps2 += __shfl_xor(ps2, o, 64); pd2 += __shfl_xor(pd2, o, 64);
        }
        if (ok && l15 == 0) {
            a_src[r * HH + 0] = ps0 * LOG2E; a_src[r * HH + 1] = ps1 * LOG2E;
            a_src[r * HH + 2] = ps2 * LOG2E;
            a_dst[r * HH + 0] = pd0 * LOG2E; a_dst[r * HH + 1] = pd1 * LOG2E;
            a_dst[r * HH + 2] = pd2 * LOG2E;
        }
    }
}

// ---------- payload fill (CSR order), 16B/edge, a_dst FOLDED IN ----------
__global__ __launch_bounds__(256) void k_fill(const float* __restrict__ ea,
                                              const int* __restrict__ ei,
                                              const float* __restrict__ a_src,
                                              const float* __restrict__ a_dst,
                                              const float* __restrict__ we,
                                              int* __restrict__ cursor,
                                              uint4* __restrict__ payload, int E) {
    int e = blockIdx.x * blockDim.x + threadIdx.x;
    if (e >= E) return;
    int s = ei[e], d = ei[E + e];
    int pos = atomicAdd(&cursor[d], 1);                  // issue early; hide RMW latency
    float attr[ED];
    #pragma unroll
    for (int j = 0; j < ED; ++j) attr[j] = ea[(size_t)e * ED + j];
    float aeh[HH], lp[HH];
    #pragma unroll
    for (int h = 0; h < HH; ++h) {
        float a = 0.f;
        #pragma unroll
        for (int j = 0; j < ED; ++j) a += attr[j] * we[j * HH + h];   // we pre-scaled
        aeh[h] = a;
        lp[h] = a_src[s * HH + h] + a_dst[d * HH + h] + a;             // all pre-scaled
    }
    uint4 pk;
    pk.x = (unsigned)f2bf(lp[0])  | ((unsigned)f2bf(lp[1])  << 16);
    pk.y = (unsigned)f2bf(lp[2])  | ((unsigned)f2bf(aeh[0]) << 16);
    pk.z = (unsigned)f2bf(aeh[1]) | ((unsigned)f2bf(aeh[2]) << 16);
    pk.w = (unsigned)s;
    payload[pos] = pk;
}

// ---------- FUSED: per-dst softmax+gather (pairwise) -> MLP -> out ----------
__global__ __launch_bounds__(256) void k_gatmlp(const unsigned short* __restrict__ xsb,
                                                const float* __restrict__ a_src,
                                                const float* __restrict__ a_dst,
                                                const int* __restrict__ off,
                                                const int* __restrict__ icnt,
                                                const uint4* __restrict__ payload,
                                                const float* __restrict__ x,
                                                const unsigned short* __restrict__ w1t,
                                                const unsigned short* __restrict__ w2t,
                                                const float* __restrict__ b1p,
                                                const float* __restrict__ g1,
                                                const float* __restrict__ be1,
                                                const float* __restrict__ b2,
                                                const float* __restrict__ g2,
                                                const float* __restrict__ be2,
                                                float* __restrict__ out, int N) {
    __shared__ float4 wbuf[8][64];                 // 8 KB (2 rows per wave)
    __shared__ unsigned short OA[16 * OAP];        // 6.25 KB, padded stride
    __shared__ unsigned short H1s[16 * 72];        // 2.25 KB
    __shared__ float red[2][4][16];                // 512 B
    int lane = threadIdx.x & 63;
    int wid  = threadIdx.x >> 6;
    const unsigned* xs32 = (const unsigned*)xsb;
    unsigned c128ml = 128u - (unsigned)lane;
    int nb16 = blockIdx.x * 16;

    // ======== gather phase: each wave handles 2 PAIRS of nodes ========
    #pragma unroll 1
    for (int t = 0; t < 2; ++t) {
        int rowa = wid * 4 + t * 2, rowb = rowa + 1;
        int na = nb16 + rowa, nbn = nb16 + rowb;
        int nac = min(na, N - 1), nbc = min(nbn, N - 1);
        int bega = off[nac], begb = off[nbc];
        int dega = (na < N) ? icnt[na] : 0;
        int degb = (nbn < N) ? icnt[nbn] : 0;

        float pda0 = 0.f, pda1 = 0.f, pda2 = 0.f, pea0 = 0.f, pea1 = 0.f, pea2 = 0.f;
        float pdb0 = 0.f, pdb1 = 0.f, pdb2 = 0.f, peb0 = 0.f, peb1 = 0.f, peb2 = 0.f;
        float aa0 = 0.f, aa1 = 0.f, aa2 = 0.f;
        float ab0 = 0.f, ab1 = 0.f, ab2 = 0.f;

        int dmax = max(dega, degb);
        for (int c0 = 0; c0 < dmax; c0 += 64) {
            int cna = min(dega - c0, 64);        // may be <= 0
            int cnb = min(degb - c0, 64);
            // --- phase A: both nodes' payload loads issued back-to-back ---
            float wa0 = 0.f, wa1 = 0.f, wa2 = 0.f, wb0 = 0.f, wb1 = 0.f, wb2 = 0.f;
            int sa = 0, sb = 0;
            if (lane < cna) {
                uint4 p = payload[bega + c0 + lane];
                wa0 = exp2f(leaky(bf_lo(p.x)));
                wa1 = exp2f(leaky(bf_hi(p.x)));
                wa2 = exp2f(leaky(bf_lo(p.y)));
                pea0 += bf_hi(p.y); pea1 += bf_lo(p.z); pea2 += bf_hi(p.z);
                pda0 += wa0; pda1 += wa1; pda2 += wa2;
                sa = (int)p.w;
            }
            if (lane < cnb) {
                uint4 p = payload[begb + c0 + lane];
                wb0 = exp2f(leaky(bf_lo(p.x)));
                wb1 = exp2f(leaky(bf_hi(p.x)));
                wb2 = exp2f(leaky(bf_lo(p.y)));
                peb0 += bf_hi(p.y); peb1 += bf_lo(p.z); peb2 += bf_hi(p.z);
                pdb0 += wb0; pdb1 += wb1; pdb2 += wb2;
                sb = (int)p.w;
            }
            wbuf[wid * 2 + 0][lane] = make_float4(wa0, wa1, wa2, __int_as_float(sa));
            wbuf[wid * 2 + 1][lane] = make_float4(wb0, wb1, wb2, __int_as_float(sb));
            // --- phase B: interleave one edge of each node per iteration ---
            int cm = max(cna, cnb);
            for (int i = 0; i < cm; ++i) {
                if (i < cna) {
                    float4 ta = wbuf[wid * 2 + 0][i];
                    unsigned ia = __umul24((unsigned)__float_as_int(ta.w), 96u) + lane;
                    unsigned va = xs32[ia];
                    float xa2 = bf2f(xsb[(ia << 1) + c128ml]);
                    aa0 += ta.x * bf_lo(va); aa1 += ta.y * bf_hi(va); aa2 += ta.z * xa2;
                }
                if (i < cnb) {
                    float4 tb = wbuf[wid * 2 + 1][i];
                    unsigned ib = __umul24((unsigned)__float_as_int(tb.w), 96u) + lane;
                    unsigned vb = xs32[ib];
                    float xb2 = bf2f(xsb[(ib << 1) + c128ml]);
                    ab0 += tb.x * bf_lo(vb); ab1 += tb.y * bf_hi(vb); ab2 += tb.z * xb2;
                }
            }
        }

        // reduce both nodes' partials (12 chains overlap)
        #pragma unroll
        for (int o = 32; o; o >>= 1) {
            pda0 += __shfl_xor(pda0, o, 64); pdb0 += __shfl_xor(pdb0, o, 64);
            pda1 += __shfl_xor(pda1, o, 64); pdb1 += __shfl_xor(pdb1, o, 64);
            pda2 += __shfl_xor(pda2, o, 64); pdb2 += __shfl_xor(pdb2, o, 64);
            pea0 += __shfl_xor(pea0, o, 64); peb0 += __shfl_xor(peb0, o, 64);
            pea1 += __shfl_xor(pea1, o, 64); peb1 += __shfl_xor(peb1, o, 64);
            pea2 += __shfl_xor(pea2, o, 64); peb2 += __shfl_xor(peb2, o, 64);
        }

        // epilogues (overlapped)
        {
            float dca = fmaxf((float)dega, 1.0f), dcb = fmaxf((float)degb, 1.0f);
            float ida = __builtin_amdgcn_rcpf(dca), idb = __builtin_amdgcn_rcpf(dcb);
            int nha = nac * HH, nhb = nbc * HH;
            float sa0 = leaky(a_src[nha + 0] + a_dst[nha + 0] + pea0 * ida);
            float sa1 = leaky(a_src[nha + 1] + a_dst[nha + 1] + pea1 * ida);
            float sa2 = leaky(a_src[nha + 2] + a_dst[nha + 2] + pea2 * ida);
            float sb0 = leaky(a_src[nhb + 0] + a_dst[nhb + 0] + peb0 * idb);
            float sb1 = leaky(a_src[nhb + 1] + a_dst[nhb + 1] + peb1 * idb);
            float sb2 = leaky(a_src[nhb + 2] + a_dst[nhb + 2] + peb2 * idb);
            float ea0 = exp2f(sa0), ea1 = exp2f(sa1), ea2 = exp2f(sa2);
            float eb0 = exp2f(sb0), eb1 = exp2f(sb1), eb2 = exp2f(sb2);
            unsigned iaa = __umul24((unsigned)nac, 96u) + lane;
            unsigned iab = __umul24((unsigned)nbc, 96u) + lane;
            unsigned vaa = xs32[iaa], vab = xs32[iab];
            float x2a = bf2f(xsb[(iaa << 1) + c128ml]);
            float x2b = bf2f(xsb[(iab << 1) + c128ml]);
            float ra0 = __builtin_amdgcn_rcpf(pda0 + ea0);
            float ra1 = __builtin_amdgcn_rcpf(pda1 + ea1);
            float ra2 = __builtin_amdgcn_rcpf(pda2 + ea2);
            float rb0 = __builtin_amdgcn_rcpf(pdb0 + eb0);
            float rb1 = __builtin_amdgcn_rcpf(pdb1 + eb1);
            float rb2 = __builtin_amdgcn_rcpf(pdb2 + eb2);
            OA[rowa * OAP +       lane] = f2bf((aa0 + ea0 * bf_lo(vaa)) * ra0);
            OA[rowa * OAP +  64 + lane] = f2bf((aa1 + ea1 * bf_hi(vaa)) * ra1);
            OA[rowa * OAP + 128 + lane] = f2bf((aa2 + ea2 * x2a) * ra2);
            OA[rowb * OAP +       lane] = f2bf((ab0 + eb0 * bf_lo(vab)) * rb0);
            OA[rowb * OAP +  64 + lane] = f2bf((ab1 + eb1 * bf_hi(vab)) * rb1);
            OA[rowb * OAP + 128 + lane] = f2bf((ab2 + eb2 * x2b) * rb2);
        }
    }
    __syncthreads();

    // ======== MLP phase: wave wid owns output cols wid*16..wid*16+15 ========
    int l15 = lane & 15, kg = (lane >> 4) * 8;
    int col = wid * 16 + l15;
    float cb1 = b1p[col], cg1 = g1[col], cbe1 = be1[col];
    float cb2 = b2[col],  cg2 = g2[col], cbe2 = be2[col];

    // GEMM1: [16 x 192] @ [192 x 16(cols of this wave)]
    f32x4 acc = (f32x4){0.f, 0.f, 0.f, 0.f};
    #pragma unroll
    for (int k0 = 0; k0 < HC; k0 += 32) {
        bf16x8 af = *(const bf16x8*)&OA[l15 * OAP + k0 + kg];
        bf16x8 bf = *(const bf16x8*)(w1t + (size_t)col * HC + k0 + kg);
        acc = __builtin_amdgcn_mfma_f32_16x16x32_bf16(af, bf, acc, 0, 0, 0);
    }

    int rj0 = (lane >> 4) * 4;
    float y[4], h1v[4];
    #pragma unroll
    for (int j = 0; j < 4; ++j) {
        int r = min(nb16 + rj0 + j, N - 1);
        y[j] = acc[j] + cb1 + x[(size_t)r * DIN + col];
        float s = y[j], q = y[j] * y[j];
        #pragma unroll
        for (int o = 1; o < 16; o <<= 1) {
            s += __shfl_xor(s, o, 64);
            q += __shfl_xor(q, o, 64);
        }
        if (l15 == 0) { red[0][wid][rj0 + j] = s; red[1][wid][rj0 + j] = q; }
    }
    __syncthreads();
    #pragma unroll
    for (int j = 0; j < 4; ++j) {
        int rj = rj0 + j;
        float s = red[0][0][rj] + red[0][1][rj] + red[0][2][rj] + red[0][3][rj];
        float q = red[1][0][rj] + red[1][1][rj] + red[1][2][rj] + red[1][3][rj];
        float m = s * (1.0f / CC);
        float var = q * (1.0f / CC) - m * m;
        float inv = rsqrtf(var + LN_EPS);
        float h = (y[j] - m) * inv * cg1 + cbe1;
        h1v[j] = h;
        H1s[rj * 72 + col] = f2bf(h);
    }
    __syncthreads();

    // GEMM2: [16 x 64] @ [64 x 16]
    f32x4 acc2 = (f32x4){0.f, 0.f, 0.f, 0.f};
    #pragma unroll
    for (int k0 = 0; k0 < CC; k0 += 32) {
        bf16x8 af = *(const bf16x8*)&H1s[l15 * 72 + k0 + kg];
        bf16x8 bf = *(const bf16x8*)(w2t + (size_t)col * CC + k0 + kg);
        acc2 = __builtin_amdgcn_mfma_f32_16x16x32_bf16(af, bf, acc2, 0, 0, 0);
    }

    float z[4];
    #pragma unroll
    for (int j = 0; j < 4; ++j) {
        z[j] = acc2[j] + cb2 + h1v[j];
        float s = z[j], q = z[j] * z[j];
        #pragma unroll
        for (int o = 1; o < 16; o <<= 1) {
            s += __shfl_xor(s, o, 64);
            q += __shfl_xor(q, o, 64);
        }
        if (l15 == 0) { red[0][wid][rj0 + j] = s; red[1][wid][rj0 + j] = q; }
    }
    __syncthreads();
    #pragma unroll
    for (int j = 0; j < 4; ++j) {
        int rj = rj0 + j;
        float s = red[0][0][rj] + red[0][1][rj] + red[0][2][rj] + red[0][3][rj];
        float q = red[1][0][rj] + red[1][1][rj] + red[1][2][rj] + red[1][3][rj];
        float m = s * (1.0f / CC);
        float var = q * (1.0f / CC) - m * m;
        float inv = rsqrtf(var + LN_EPS);
        int r = nb16 + rj;
        if (r < N)
            out[(size_t)r * CC + col] = (z[j] - m) * inv * cg2 + cbe2;
    }
}

extern "C" void kernel_launch(void* const* d_in, const int* in_sizes, int n_in,
                              void* d_out, int out_size, void* d_ws, size_t ws_size,
                              hipStream_t stream) {
    const float* x          = (const float*)d_in[0];
    const float* edge_attr  = (const float*)d_in[1];
    const float* lin_w      = (const float*)d_in[2];
    const float* att_src    = (const float*)d_in[3];
    const float* att_dst    = (const float*)d_in[4];
    const float* lin_edge_w = (const float*)d_in[5];
    const float* att_edge   = (const float*)d_in[6];
    const float* gat_bias   = (const float*)d_in[7];
    const float* w1         = (const float*)d_in[8];
    const float* b1         = (const float*)d_in[9];
    const float* ln1_g      = (const float*)d_in[10];
    const float* ln1_b      = (const float*)d_in[11];
    const float* w2         = (const float*)d_in[12];
    const float* b2         = (const float*)d_in[13];
    const float* ln2_g      = (const float*)d_in[14];
    const float* ln2_b      = (const float*)d_in[15];
    const int*   ei         = (const int*)d_in[16];
    float* out = (float*)d_out;

    const int N = in_sizes[0] / DIN;
    const int E = in_sizes[1] / ED;
    const int nb_scan = (N + 255) / 256;
    const int nbx = (N + 63) / 64;

    char* ws = (char*)d_ws;
    size_t off_b = 0;
    auto alloc = [&](size_t bytes) {
        size_t o = off_b;
        off_b = (off_b + bytes + 255) & ~(size_t)255;
        return o;
    };
    // zeroed region first (single memset)
    int* icnt = (int*)(ws + alloc((size_t)N * 4));
    int* gtot = (int*)(ws + alloc(4));
    size_t zero_bytes = off_b;
    // fully-overwritten region
    unsigned short* xsb = (unsigned short*)(ws + alloc((size_t)N * HC * 2));
    float*  a_srcb  = (float*)(ws + alloc((size_t)N * HH * 4));
    float*  a_dstb  = (float*)(ws + alloc((size_t)N * HH * 4));
    int*    offb    = (int*)(ws + alloc((size_t)N * 4));
    int*    cursor  = (int*)(ws + alloc((size_t)N * 4));
    uint4*  payload = (uint4*)(ws + alloc((size_t)E * 16));
    unsigned short* linwt = (unsigned short*)(ws + alloc((size_t)HC * DIN * 2));
    unsigned short* w1t   = (unsigned short*)(ws + alloc((size_t)DIN * HC * 2));
    unsigned short* w2t   = (unsigned short*)(ws + alloc((size_t)CC * CC * 2));
    float* b1p = (float*)(ws + alloc((size_t)CC * 4));
    float* we  = (float*)(ws + alloc((size_t)ED * HH * 4));
    (void)ws_size; (void)n_in; (void)out_size;

    hipMemsetAsync(d_ws, 0, zero_bytes, stream);

    k_prep_cnt<<<PREP_BLOCKS + 1 + (E + 255) / 256, 256, 0, stream>>>(
        lin_w, w1, w2, b1, gat_bias, lin_edge_w, att_edge,
        linwt, w1t, w2t, b1p, we, ei, icnt, E);
    k_xs<<<nbx + nb_scan, 256, 0, stream>>>(x, linwt, att_src, att_dst, xsb,
                                            a_srcb, a_dstb, icnt, gtot, offb, cursor,
                                            N, nbx);
    k_fill<<<(E + 255) / 256, 256, 0, stream>>>(edge_attr, ei, a_srcb, a_dstb, we, cursor,
                                                payload, E);
    k_gatmlp<<<(N + 15) / 16, 256, 0, stream>>>(xsb, a_srcb, a_dstb, offb, icnt, payload,
                                                x, w1t, w2t, b1p, ln1_g, ln1_b,
                                                b2, ln2_g, ln2_b, out, N);
}

// Round 17
// 176.471 us; speedup vs baseline: 1.1299x; 1.1299x over previous
//
#include <hip/hip_runtime.h>

// GraphTransformerBlock2: GATConv(H=3,C=64, edge_dim=5, self-loops w/ mean fill)
// -> linear1 -> LN(x + .) -> linear2 -> LN(lin + .)
// All float32 I/O. edge_index int32 (2,E): src=ei[0:E], dst=ei[E:2E].
//
// R16: revert R15's pairwise interleave (runtime branches in the hot loop
//      blocked unrolling: 77.7 -> 96.8us). Back to R14's 1-node/wave body,
//      with phase-B unroll deepened 2 -> 3 (6 gather loads in flight;
//      VGPR ~44 < 64 = wave-cap limit, so free).

#define HH 3
#define CC 64
#define DIN 64
#define ED 5
#define HC 192
#define OAP 200                 // padded OA row stride (u16)
#define NEG_SLOPE 0.2f
#define LN_EPS 1e-5f
#define LOG2E 1.44269504f

typedef __attribute__((ext_vector_type(8))) short bf16x8;
typedef __attribute__((ext_vector_type(4))) float f32x4;

__device__ __forceinline__ float leaky(float l) { return fmaxf(l, NEG_SLOPE * l); }

__device__ __forceinline__ unsigned short f2bf(float f) {
    unsigned u = __float_as_uint(f);
    unsigned r = (u + 0x7FFFu + ((u >> 16) & 1u)) >> 16;   // RNE
    return (unsigned short)r;
}
__device__ __forceinline__ float bf2f(unsigned short u) {
    return __uint_as_float((unsigned)u << 16);
}
__device__ __forceinline__ float bf_lo(unsigned v) { return __uint_as_float(v << 16); }
__device__ __forceinline__ float bf_hi(unsigned v) { return __uint_as_float(v & 0xFFFF0000u); }

__device__ __forceinline__ bf16x8 pack8(float4 a, float4 b) {
    bf16x8 r;
    r[0] = (short)f2bf(a.x); r[1] = (short)f2bf(a.y);
    r[2] = (short)f2bf(a.z); r[3] = (short)f2bf(a.w);
    r[4] = (short)f2bf(b.x); r[5] = (short)f2bf(b.y);
    r[6] = (short)f2bf(b.z); r[7] = (short)f2bf(b.w);
    return r;
}

// ---------- prep: transposes (blocks 0..27), b1p+we (block 28), cnt (rest) ----------
#define PREP_TRANS (HC*DIN + DIN*HC + CC*CC)
#define PREP_BLOCKS 28
__global__ __launch_bounds__(256) void k_prep_cnt(const float* __restrict__ lin_w,
                                                  const float* __restrict__ w1,
                                                  const float* __restrict__ w2,
                                                  const float* __restrict__ b1,
                                                  const float* __restrict__ gat_bias,
                                                  const float* __restrict__ lin_edge_w,
                                                  const float* __restrict__ att_edge,
                                                  unsigned short* __restrict__ linwt,
                                                  unsigned short* __restrict__ w1t,
                                                  unsigned short* __restrict__ w2t,
                                                  float* __restrict__ b1p,
                                                  float* __restrict__ we,
                                                  const int* __restrict__ ei,
                                                  int* __restrict__ icnt, int E) {
    if (blockIdx.x < PREP_BLOCKS) {
        for (int i = blockIdx.x * 256 + threadIdx.x; i < PREP_TRANS; i += PREP_BLOCKS * 256) {
            if (i < HC * DIN) {
                int c = i >> 6, k = i & 63;
                linwt[i] = f2bf(lin_w[k * HC + c]);
            } else if (i < 2 * HC * DIN) {
                int j = i - HC * DIN;
                int c = j / HC, k = j - c * HC;
                w1t[j] = f2bf(w1[k * CC + c]);
            } else {
                int j = i - 2 * HC * DIN;
                int c = j >> 6, k = j & 63;
                w2t[j] = f2bf(w2[k * CC + c]);
            }
        }
    } else if (blockIdx.x == PREP_BLOCKS) {
        __shared__ float pb[4][CC];
        __shared__ float pw[15][16];
        int t = threadIdx.x;
        int c = t & 63, kq = t >> 6;
        float s = 0.f;
        for (int k = kq * 48; k < kq * 48 + 48; ++k)
            s += gat_bias[k] * w1[k * CC + c];
        pb[kq][c] = s;
        int q = t >> 4, cq = t & 15;
        if (q < 15) {
            int d = q / HH, h = q - d * HH;
            float s2 = 0.f;
            #pragma unroll
            for (int c2 = cq * 4; c2 < cq * 4 + 4; ++c2)
                s2 += lin_edge_w[d * HC + h * CC + c2] * att_edge[h * CC + c2];
            pw[q][cq] = s2;
        }
        __syncthreads();
        if (t < CC) b1p[t] = b1[t] + pb[0][t] + pb[1][t] + pb[2][t] + pb[3][t];
        if (t < 15) {
            float tot = 0.f;
            #pragma unroll
            for (int i2 = 0; i2 < 16; ++i2) tot += pw[t][i2];
            we[t] = tot * LOG2E;
        }
    } else {
        int nb = gridDim.x - PREP_BLOCKS - 1;
        for (int e = (blockIdx.x - PREP_BLOCKS - 1) * 256 + threadIdx.x; e < E; e += nb * 256)
            atomicAdd(&icnt[ei[E + e]], 1);
    }
}

// ---------- xs = x @ lin_w (MFMA) -> packed xsb + a_src/a_dst;  scan fused ----------
__global__ __launch_bounds__(256) void k_xs(const float* __restrict__ x,
                                            const unsigned short* __restrict__ linwt,
                                            const float* __restrict__ att_src,
                                            const float* __restrict__ att_dst,
                                            unsigned short* __restrict__ xsb,
                                            float* __restrict__ a_src,
                                            float* __restrict__ a_dst,
                                            const int* __restrict__ icnt,
                                            int* __restrict__ gtot,
                                            int* __restrict__ off,
                                            int* __restrict__ cursor,
                                            int N, int nbx) {
    __shared__ int wt[4];
    __shared__ int base_sh;
    if ((int)blockIdx.x >= nbx) {
        int bid = blockIdx.x - nbx;
        int i = bid * 256 + threadIdx.x;
        int lane = threadIdx.x & 63, wid = threadIdx.x >> 6;
        int v = (i < N) ? icnt[i] : 0;
        int incl = v;
        #pragma unroll
        for (int o = 1; o < 64; o <<= 1) {
            int u = __shfl_up(incl, o, 64);
            if (lane >= o) incl += u;
        }
        if (lane == 63) wt[wid] = incl;
        __syncthreads();
        if (threadIdx.x == 0)
            base_sh = atomicAdd(gtot, wt[0] + wt[1] + wt[2] + wt[3]);
        __syncthreads();
        int wpre = 0;
        for (int w2 = 0; w2 < wid; ++w2) wpre += wt[w2];
        int excl = base_sh + wpre + incl - v;
        if (i < N) { off[i] = excl; cursor[i] = excl; }
        return;
    }

    int lane = threadIdx.x & 63, w = threadIdx.x >> 6;
    int l15 = lane & 15, kg = (lane >> 4) * 8;
    int nb = blockIdx.x * 64;
    int arow = nb + w * 16 + l15;
    int arow_c = min(arow, N - 1);

    f32x4 acc[12];
    #pragma unroll
    for (int ct = 0; ct < 12; ++ct) acc[ct] = (f32x4){0.f, 0.f, 0.f, 0.f};

    #pragma unroll
    for (int k0 = 0; k0 < DIN; k0 += 32) {
        const float* ap = x + (size_t)arow_c * DIN + k0 + kg;
        float4 a0 = *(const float4*)ap;
        float4 a1 = *(const float4*)(ap + 4);
        bf16x8 af = pack8(a0, a1);
        #pragma unroll
        for (int ct = 0; ct < 12; ++ct) {
            bf16x8 bf = *(const bf16x8*)(linwt + (size_t)(ct * 16 + l15) * DIN + k0 + kg);
            acc[ct] = __builtin_amdgcn_mfma_f32_16x16x32_bf16(af, bf, acc[ct], 0, 0, 0);
        }
    }

    float asv[12], adv[12];
    #pragma unroll
    for (int ct = 0; ct < 12; ++ct) {
        int c = ct * 16 + l15;
        asv[ct] = att_src[c]; adv[ct] = att_dst[c];
    }

    int rbase = nb + w * 16 + (lane >> 4) * 4;
    #pragma unroll
    for (int j = 0; j < 4; ++j) {
        int r = rbase + j;
        bool ok = r < N;
        float ps0 = 0.f, ps1 = 0.f, ps2 = 0.f, pd0 = 0.f, pd1 = 0.f, pd2 = 0.f;
        #pragma unroll
        for (int ct = 0; ct < 12; ++ct) {
            float v = acc[ct][j];
            float s = v * asv[ct], d = v * adv[ct];
            if (ct < 4)      { ps0 += s; pd0 += d; }
            else if (ct < 8) { ps1 += s; pd1 += d; }
            else             { ps2 += s; pd2 += d; }
        }
        if (ok) {
            unsigned* row32 = (unsigned*)(xsb + (size_t)r * HC);
            #pragma unroll
            for (int ct = 0; ct < 4; ++ct) {
                int c = ct * 16 + l15;
                row32[c] = (unsigned)f2bf(acc[ct][j]) | ((unsigned)f2bf(acc[ct + 4][j]) << 16);
                xsb[(size_t)r * HC + 128 + c] = f2bf(acc[ct + 8][j]);
            }
        }
        #pragma unroll
        for (int o = 1; o < 16; o <<= 1) {
            ps0 += __shfl_xor(ps0, o, 64); pd0 += __shfl_xor(pd0, o, 64);
            ps1 += __shfl_xor(ps1, o, 64); pd1 += __shfl_xor(pd1, o, 64);
            ps2 += __shfl_xor(ps2, o, 64); pd2 += __shfl_xor(pd2, o, 64);
        }
        if (ok && l15 == 0) {
            a_src[r * HH + 0] = ps0 * LOG2E; a_src[r * HH + 1] = ps1 * LOG2E;
            a_src[r * HH + 2] = ps2 * LOG2E;
            a_dst[r * HH + 0] = pd0 * LOG2E; a_dst[r * HH + 1] = pd1 * LOG2E;
            a_dst[r * HH + 2] = pd2 * LOG2E;
        }
    }
}

// ---------- payload fill (CSR order), 16B/edge, a_dst FOLDED IN ----------
__global__ __launch_bounds__(256) void k_fill(const float* __restrict__ ea,
                                              const int* __restrict__ ei,
                                              const float* __restrict__ a_src,
                                              const float* __restrict__ a_dst,
                                              const float* __restrict__ we,
                                              int* __restrict__ cursor,
                                              uint4* __restrict__ payload, int E) {
    int e = blockIdx.x * blockDim.x + threadIdx.x;
    if (e >= E) return;
    int s = ei[e], d = ei[E + e];
    int pos = atomicAdd(&cursor[d], 1);                  // issue early; hide RMW latency
    float attr[ED];
    #pragma unroll
    for (int j = 0; j < ED; ++j) attr[j] = ea[(size_t)e * ED + j];
    float aeh[HH], lp[HH];
    #pragma unroll
    for (int h = 0; h < HH; ++h) {
        float a = 0.f;
        #pragma unroll
        for (int j = 0; j < ED; ++j) a += attr[j] * we[j * HH + h];   // we pre-scaled
        aeh[h] = a;
        lp[h] = a_src[s * HH + h] + a_dst[d * HH + h] + a;             // all pre-scaled
    }
    uint4 pk;
    pk.x = (unsigned)f2bf(lp[0])  | ((unsigned)f2bf(lp[1])  << 16);
    pk.y = (unsigned)f2bf(lp[2])  | ((unsigned)f2bf(aeh[0]) << 16);
    pk.z = (unsigned)f2bf(aeh[1]) | ((unsigned)f2bf(aeh[2]) << 16);
    pk.w = (unsigned)s;
    payload[pos] = pk;
}

// ---------- FUSED: per-dst softmax+gather (16-node tile) -> MLP -> out ----------
__global__ __launch_bounds__(256) void k_gatmlp(const unsigned short* __restrict__ xsb,
                                                const float* __restrict__ a_src,
                                                const float* __restrict__ a_dst,
                                                const int* __restrict__ off,
                                                const int* __restrict__ icnt,
                                                const uint4* __restrict__ payload,
                                                const float* __restrict__ x,
                                                const unsigned short* __restrict__ w1t,
                                                const unsigned short* __restrict__ w2t,
                                                const float* __restrict__ b1p,
                                                const float* __restrict__ g1,
                                                const float* __restrict__ be1,
                                                const float* __restrict__ b2,
                                                const float* __restrict__ g2,
                                                const float* __restrict__ be2,
                                                float* __restrict__ out, int N) {
    __shared__ float4 wbuf[4][64];                 // 4 KB
    __shared__ unsigned short OA[16 * OAP];        // 6.25 KB, padded stride
    __shared__ unsigned short H1s[16 * 72];        // 2.25 KB
    __shared__ float red[2][4][16];                // 512 B
    int lane = threadIdx.x & 63;
    int wid  = threadIdx.x >> 6;
    const unsigned* xs32 = (const unsigned*)xsb;
    unsigned c128ml = 128u - (unsigned)lane;
    int nb16 = blockIdx.x * 16;

    // ======== gather phase: each wave handles 4 nodes serially ========
    #pragma unroll 1
    for (int t = 0; t < 4; ++t) {
        int row = wid * 4 + t;
        int n = nb16 + row;
        if (n < N) {
            int beg = off[n];
            int deg = icnt[n];
            float pden0 = 0.f, pden1 = 0.f, pden2 = 0.f;
            float pae0 = 0.f, pae1 = 0.f, pae2 = 0.f;
            float a0A = 0.f, a1A = 0.f, a2A = 0.f;
            float a0B = 0.f, a1B = 0.f, a2B = 0.f;
            float a0C = 0.f, a1C = 0.f, a2C = 0.f;

            for (int c0 = 0; c0 < deg; c0 += 64) {
                int cn = min(deg - c0, 64);
                float w0 = 0.f, w1 = 0.f, w2 = 0.f;
                int src = 0;
                if (lane < cn) {
                    uint4 p = payload[beg + c0 + lane];
                    w0 = exp2f(leaky(bf_lo(p.x)));
                    w1 = exp2f(leaky(bf_hi(p.x)));
                    w2 = exp2f(leaky(bf_lo(p.y)));
                    pae0 += bf_hi(p.y);
                    pae1 += bf_lo(p.z);
                    pae2 += bf_hi(p.z);
                    pden0 += w0; pden1 += w1; pden2 += w2;
                    src = (int)p.w;
                }
                wbuf[wid][lane] = make_float4(w0, w1, w2, __int_as_float(src));
                // --- phase B: 3-wide unroll, 6 gather loads in flight ---
                int i = 0;
                for (; i + 3 <= cn; i += 3) {
                    float4 ta = wbuf[wid][i];
                    float4 tb = wbuf[wid][i + 1];
                    float4 tc = wbuf[wid][i + 2];
                    unsigned ia = __umul24((unsigned)__float_as_int(ta.w), 96u) + lane;
                    unsigned ib = __umul24((unsigned)__float_as_int(tb.w), 96u) + lane;
                    unsigned ic = __umul24((unsigned)__float_as_int(tc.w), 96u) + lane;
                    unsigned va = xs32[ia];
                    unsigned vb = xs32[ib];
                    unsigned vc = xs32[ic];
                    float xa2 = bf2f(xsb[(ia << 1) + c128ml]);
                    float xb2 = bf2f(xsb[(ib << 1) + c128ml]);
                    float xc2 = bf2f(xsb[(ic << 1) + c128ml]);
                    a0A += ta.x * bf_lo(va); a1A += ta.y * bf_hi(va); a2A += ta.z * xa2;
                    a0B += tb.x * bf_lo(vb); a1B += tb.y * bf_hi(vb); a2B += tb.z * xb2;
                    a0C += tc.x * bf_lo(vc); a1C += tc.y * bf_hi(vc); a2C += tc.z * xc2;
                }
                for (; i < cn; ++i) {
                    float4 ta = wbuf[wid][i];
                    unsigned ia = __umul24((unsigned)__float_as_int(ta.w), 96u) + lane;
                    unsigned va = xs32[ia];
                    a0A += ta.x * bf_lo(va);
                    a1A += ta.y * bf_hi(va);
                    a2A += ta.z * bf2f(xsb[(ia << 1) + c128ml]);
                }
            }

            #pragma unroll
            for (int o = 32; o; o >>= 1) {
                pden0 += __shfl_xor(pden0, o, 64);
                pden1 += __shfl_xor(pden1, o, 64);
                pden2 += __shfl_xor(pden2, o, 64);
                pae0  += __shfl_xor(pae0, o, 64);
                pae1  += __shfl_xor(pae1, o, 64);
                pae2  += __shfl_xor(pae2, o, 64);
            }

            float dc = fmaxf((float)deg, 1.0f);
            float inv_dc = __builtin_amdgcn_rcpf(dc);
            float sl0 = leaky(a_src[n * HH + 0] + a_dst[n * HH + 0] + pae0 * inv_dc);
            float sl1 = leaky(a_src[n * HH + 1] + a_dst[n * HH + 1] + pae1 * inv_dc);
            float sl2 = leaky(a_src[n * HH + 2] + a_dst[n * HH + 2] + pae2 * inv_dc);
            float e0 = exp2f(sl0), e1 = exp2f(sl1), e2 = exp2f(sl2);
            unsigned ian = __umul24((unsigned)n, 96u) + lane;
            unsigned van = xs32[ian];
            float xn2 = bf2f(xsb[(ian << 1) + c128ml]);
            float r0 = __builtin_amdgcn_rcpf(pden0 + e0);
            float r1 = __builtin_amdgcn_rcpf(pden1 + e1);
            float r2 = __builtin_amdgcn_rcpf(pden2 + e2);
            OA[row * OAP +       lane] = f2bf((a0A + a0B + a0C + e0 * bf_lo(van)) * r0);
            OA[row * OAP +  64 + lane] = f2bf((a1A + a1B + a1C + e1 * bf_hi(van)) * r1);
            OA[row * OAP + 128 + lane] = f2bf((a2A + a2B + a2C + e2 * xn2) * r2);
        } else {
            OA[row * OAP +       lane] = 0;
            OA[row * OAP +  64 + lane] = 0;
            OA[row * OAP + 128 + lane] = 0;
        }
    }
    __syncthreads();

    // ======== MLP phase: wave wid owns output cols wid*16..wid*16+15 ========
    int l15 = lane & 15, kg = (lane >> 4) * 8;
    int col = wid * 16 + l15;
    float cb1 = b1p[col], cg1 = g1[col], cbe1 = be1[col];
    float cb2 = b2[col],  cg2 = g2[col], cbe2 = be2[col];

    // GEMM1: [16 x 192] @ [192 x 16(cols of this wave)]
    f32x4 acc = (f32x4){0.f, 0.f, 0.f, 0.f};
    #pragma unroll
    for (int k0 = 0; k0 < HC; k0 += 32) {
        bf16x8 af = *(const bf16x8*)&OA[l15 * OAP + k0 + kg];
        bf16x8 bf = *(const bf16x8*)(w1t + (size_t)col * HC + k0 + kg);
        acc = __builtin_amdgcn_mfma_f32_16x16x32_bf16(af, bf, acc, 0, 0, 0);
    }

    int rj0 = (lane >> 4) * 4;
    float y[4], h1v[4];
    #pragma unroll
    for (int j = 0; j < 4; ++j) {
        int r = min(nb16 + rj0 + j, N - 1);
        y[j] = acc[j] + cb1 + x[(size_t)r * DIN + col];
        float s = y[j], q = y[j] * y[j];
        #pragma unroll
        for (int o = 1; o < 16; o <<= 1) {
            s += __shfl_xor(s, o, 64);
            q += __shfl_xor(q, o, 64);
        }
        if (l15 == 0) { red[0][wid][rj0 + j] = s; red[1][wid][rj0 + j] = q; }
    }
    __syncthreads();
    #pragma unroll
    for (int j = 0; j < 4; ++j) {
        int rj = rj0 + j;
        float s = red[0][0][rj] + red[0][1][rj] + red[0][2][rj] + red[0][3][rj];
        float q = red[1][0][rj] + red[1][1][rj] + red[1][2][rj] + red[1][3][rj];
        float m = s * (1.0f / CC);
        float var = q * (1.0f / CC) - m * m;
        float inv = rsqrtf(var + LN_EPS);
        float h = (y[j] - m) * inv * cg1 + cbe1;
        h1v[j] = h;
        H1s[rj * 72 + col] = f2bf(h);
    }
    __syncthreads();

    // GEMM2: [16 x 64] @ [64 x 16]
    f32x4 acc2 = (f32x4){0.f, 0.f, 0.f, 0.f};
    #pragma unroll
    for (int k0 = 0; k0 < CC; k0 += 32) {
        bf16x8 af = *(const bf16x8*)&H1s[l15 * 72 + k0 + kg];
        bf16x8 bf = *(const bf16x8*)(w2t + (size_t)col * CC + k0 + kg);
        acc2 = __builtin_amdgcn_mfma_f32_16x16x32_bf16(af, bf, acc2, 0, 0, 0);
    }

    float z[4];
    #pragma unroll
    for (int j = 0; j < 4; ++j) {
        z[j] = acc2[j] + cb2 + h1v[j];
        float s = z[j], q = z[j] * z[j];
        #pragma unroll
        for (int o = 1; o < 16; o <<= 1) {
            s += __shfl_xor(s, o, 64);
            q += __shfl_xor(q, o, 64);
        }
        if (l15 == 0) { red[0][wid][rj0 + j] = s; red[1][wid][rj0 + j] = q; }
    }
    __syncthreads();
    #pragma unroll
    for (int j = 0; j < 4; ++j) {
        int rj = rj0 + j;
        float s = red[0][0][rj] + red[0][1][rj] + red[0][2][rj] + red[0][3][rj];
        float q = red[1][0][rj] + red[1][1][rj] + red[1][2][rj] + red[1][3][rj];
        float m = s * (1.0f / CC);
        float var = q * (1.0f / CC) - m * m;
        float inv = rsqrtf(var + LN_EPS);
        int r = nb16 + rj;
        if (r < N)
            out[(size_t)r * CC + col] = (z[j] - m) * inv * cg2 + cbe2;
    }
}

extern "C" void kernel_launch(void* const* d_in, const int* in_sizes, int n_in,
                              void* d_out, int out_size, void* d_ws, size_t ws_size,
                              hipStream_t stream) {
    const float* x          = (const float*)d_in[0];
    const float* edge_attr  = (const float*)d_in[1];
    const float* lin_w      = (const float*)d_in[2];
    const float* att_src    = (const float*)d_in[3];
    const float* att_dst    = (const float*)d_in[4];
    const float* lin_edge_w = (const float*)d_in[5];
    const float* att_edge   = (const float*)d_in[6];
    const float* gat_bias   = (const float*)d_in[7];
    const float* w1         = (const float*)d_in[8];
    const float* b1         = (const float*)d_in[9];
    const float* ln1_g      = (const float*)d_in[10];
    const float* ln1_b      = (const float*)d_in[11];
    const float* w2         = (const float*)d_in[12];
    const float* b2         = (const float*)d_in[13];
    const float* ln2_g      = (const float*)d_in[14];
    const float* ln2_b      = (const float*)d_in[15];
    const int*   ei         = (const int*)d_in[16];
    float* out = (float*)d_out;

    const int N = in_sizes[0] / DIN;
    const int E = in_sizes[1] / ED;
    const int nb_scan = (N + 255) / 256;
    const int nbx = (N + 63) / 64;

    char* ws = (char*)d_ws;
    size_t off_b = 0;
    auto alloc = [&](size_t bytes) {
        size_t o = off_b;
        off_b = (off_b + bytes + 255) & ~(size_t)255;
        return o;
    };
    // zeroed region first (single memset)
    int* icnt = (int*)(ws + alloc((size_t)N * 4));
    int* gtot = (int*)(ws + alloc(4));
    size_t zero_bytes = off_b;
    // fully-overwritten region
    unsigned short* xsb = (unsigned short*)(ws + alloc((size_t)N * HC * 2));
    float*  a_srcb  = (float*)(ws + alloc((size_t)N * HH * 4));
    float*  a_dstb  = (float*)(ws + alloc((size_t)N * HH * 4));
    int*    offb    = (int*)(ws + alloc((size_t)N * 4));
    int*    cursor  = (int*)(ws + alloc((size_t)N * 4));
    uint4*  payload = (uint4*)(ws + alloc((size_t)E * 16));
    unsigned short* linwt = (unsigned short*)(ws + alloc((size_t)HC * DIN * 2));
    unsigned short* w1t   = (unsigned short*)(ws + alloc((size_t)DIN * HC * 2));
    unsigned short* w2t   = (unsigned short*)(ws + alloc((size_t)CC * CC * 2));
    float* b1p = (float*)(ws + alloc((size_t)CC * 4));
    float* we  = (float*)(ws + alloc((size_t)ED * HH * 4));
    (void)ws_size; (void)n_in; (void)out_size;

    hipMemsetAsync(d_ws, 0, zero_bytes, stream);

    k_prep_cnt<<<PREP_BLOCKS + 1 + (E + 255) / 256, 256, 0, stream>>>(
        lin_w, w1, w2, b1, gat_bias, lin_edge_w, att_edge,
        linwt, w1t, w2t, b1p, we, ei, icnt, E);
    k_xs<<<nbx + nb_scan, 256, 0, stream>>>(x, linwt, att_src, att_dst, xsb,
                                            a_srcb, a_dstb, icnt, gtot, offb, cursor,
                                            N, nbx);
    k_fill<<<(E + 255) / 256, 256, 0, stream>>>(edge_attr, ei, a_srcb, a_dstb, we, cursor,
                                                payload, E);
    k_gatmlp<<<(N + 15) / 16, 256, 0, stream>>>(xsb, a_srcb, a_dstb, offb, icnt, payload,
                                                x, w1t, w2t, b1p, ln1_g, ln1_b,
                                                b2, ln2_g, ln2_b, out, N);
}

// Round 18
// 175.754 us; speedup vs baseline: 1.1345x; 1.0041x over previous
//
#include <hip/hip_runtime.h>

// GraphTransformerBlock2: GATConv(H=3,C=64, edge_dim=5, self-loops w/ mean fill)
// -> linear1 -> LN(x + .) -> linear2 -> LN(lin + .)
// All float32 I/O. edge_index int32 (2,E): src=ei[0:E], dst=ei[E:2E].
//
// R17: software-pipeline the gather phase's 4-node loop. Registers carry
//      (begC,degC,pC) = next node's descriptor + first payload chunk;
//      descriptor loads for t+1 issue at top of t, payload prefetch issues
//      after phase A -> both resolve under phase B (~1000 cyc). Kills the
//      ~700-cycle serial latency head paid 4x per wave. Phase B stays
//      3-wide (R16). No arrays -> no scratch (rule #20).

#define HH 3
#define CC 64
#define DIN 64
#define ED 5
#define HC 192
#define OAP 200                 // padded OA row stride (u16)
#define NEG_SLOPE 0.2f
#define LN_EPS 1e-5f
#define LOG2E 1.44269504f

typedef __attribute__((ext_vector_type(8))) short bf16x8;
typedef __attribute__((ext_vector_type(4))) float f32x4;

__device__ __forceinline__ float leaky(float l) { return fmaxf(l, NEG_SLOPE * l); }

__device__ __forceinline__ unsigned short f2bf(float f) {
    unsigned u = __float_as_uint(f);
    unsigned r = (u + 0x7FFFu + ((u >> 16) & 1u)) >> 16;   // RNE
    return (unsigned short)r;
}
__device__ __forceinline__ float bf2f(unsigned short u) {
    return __uint_as_float((unsigned)u << 16);
}
__device__ __forceinline__ float bf_lo(unsigned v) { return __uint_as_float(v << 16); }
__device__ __forceinline__ float bf_hi(unsigned v) { return __uint_as_float(v & 0xFFFF0000u); }

__device__ __forceinline__ bf16x8 pack8(float4 a, float4 b) {
    bf16x8 r;
    r[0] = (short)f2bf(a.x); r[1] = (short)f2bf(a.y);
    r[2] = (short)f2bf(a.z); r[3] = (short)f2bf(a.w);
    r[4] = (short)f2bf(b.x); r[5] = (short)f2bf(b.y);
    r[6] = (short)f2bf(b.z); r[7] = (short)f2bf(b.w);
    return r;
}

// ---------- prep: transposes (blocks 0..27), b1p+we (block 28), cnt (rest) ----------
#define PREP_TRANS (HC*DIN + DIN*HC + CC*CC)
#define PREP_BLOCKS 28
__global__ __launch_bounds__(256) void k_prep_cnt(const float* __restrict__ lin_w,
                                                  const float* __restrict__ w1,
                                                  const float* __restrict__ w2,
                                                  const float* __restrict__ b1,
                                                  const float* __restrict__ gat_bias,
                                                  const float* __restrict__ lin_edge_w,
                                                  const float* __restrict__ att_edge,
                                                  unsigned short* __restrict__ linwt,
                                                  unsigned short* __restrict__ w1t,
                                                  unsigned short* __restrict__ w2t,
                                                  float* __restrict__ b1p,
                                                  float* __restrict__ we,
                                                  const int* __restrict__ ei,
                                                  int* __restrict__ icnt, int E) {
    if (blockIdx.x < PREP_BLOCKS) {
        for (int i = blockIdx.x * 256 + threadIdx.x; i < PREP_TRANS; i += PREP_BLOCKS * 256) {
            if (i < HC * DIN) {
                int c = i >> 6, k = i & 63;
                linwt[i] = f2bf(lin_w[k * HC + c]);
            } else if (i < 2 * HC * DIN) {
                int j = i - HC * DIN;
                int c = j / HC, k = j - c * HC;
                w1t[j] = f2bf(w1[k * CC + c]);
            } else {
                int j = i - 2 * HC * DIN;
                int c = j >> 6, k = j & 63;
                w2t[j] = f2bf(w2[k * CC + c]);
            }
        }
    } else if (blockIdx.x == PREP_BLOCKS) {
        __shared__ float pb[4][CC];
        __shared__ float pw[15][16];
        int t = threadIdx.x;
        int c = t & 63, kq = t >> 6;
        float s = 0.f;
        for (int k = kq * 48; k < kq * 48 + 48; ++k)
            s += gat_bias[k] * w1[k * CC + c];
        pb[kq][c] = s;
        int q = t >> 4, cq = t & 15;
        if (q < 15) {
            int d = q / HH, h = q - d * HH;
            float s2 = 0.f;
            #pragma unroll
            for (int c2 = cq * 4; c2 < cq * 4 + 4; ++c2)
                s2 += lin_edge_w[d * HC + h * CC + c2] * att_edge[h * CC + c2];
            pw[q][cq] = s2;
        }
        __syncthreads();
        if (t < CC) b1p[t] = b1[t] + pb[0][t] + pb[1][t] + pb[2][t] + pb[3][t];
        if (t < 15) {
            float tot = 0.f;
            #pragma unroll
            for (int i2 = 0; i2 < 16; ++i2) tot += pw[t][i2];
            we[t] = tot * LOG2E;
        }
    } else {
        int nb = gridDim.x - PREP_BLOCKS - 1;
        for (int e = (blockIdx.x - PREP_BLOCKS - 1) * 256 + threadIdx.x; e < E; e += nb * 256)
            atomicAdd(&icnt[ei[E + e]], 1);
    }
}

// ---------- xs = x @ lin_w (MFMA) -> packed xsb + a_src/a_dst;  scan fused ----------
__global__ __launch_bounds__(256) void k_xs(const float* __restrict__ x,
                                            const unsigned short* __restrict__ linwt,
                                            const float* __restrict__ att_src,
                                            const float* __restrict__ att_dst,
                                            unsigned short* __restrict__ xsb,
                                            float* __restrict__ a_src,
                                            float* __restrict__ a_dst,
                                            const int* __restrict__ icnt,
                                            int* __restrict__ gtot,
                                            int* __restrict__ off,
                                            int* __restrict__ cursor,
                                            int N, int nbx) {
    __shared__ int wt[4];
    __shared__ int base_sh;
    if ((int)blockIdx.x >= nbx) {
        int bid = blockIdx.x - nbx;
        int i = bid * 256 + threadIdx.x;
        int lane = threadIdx.x & 63, wid = threadIdx.x >> 6;
        int v = (i < N) ? icnt[i] : 0;
        int incl = v;
        #pragma unroll
        for (int o = 1; o < 64; o <<= 1) {
            int u = __shfl_up(incl, o, 64);
            if (lane >= o) incl += u;
        }
        if (lane == 63) wt[wid] = incl;
        __syncthreads();
        if (threadIdx.x == 0)
            base_sh = atomicAdd(gtot, wt[0] + wt[1] + wt[2] + wt[3]);
        __syncthreads();
        int wpre = 0;
        for (int w2 = 0; w2 < wid; ++w2) wpre += wt[w2];
        int excl = base_sh + wpre + incl - v;
        if (i < N) { off[i] = excl; cursor[i] = excl; }
        return;
    }

    int lane = threadIdx.x & 63, w = threadIdx.x >> 6;
    int l15 = lane & 15, kg = (lane >> 4) * 8;
    int nb = blockIdx.x * 64;
    int arow = nb + w * 16 + l15;
    int arow_c = min(arow, N - 1);

    f32x4 acc[12];
    #pragma unroll
    for (int ct = 0; ct < 12; ++ct) acc[ct] = (f32x4){0.f, 0.f, 0.f, 0.f};

    #pragma unroll
    for (int k0 = 0; k0 < DIN; k0 += 32) {
        const float* ap = x + (size_t)arow_c * DIN + k0 + kg;
        float4 a0 = *(const float4*)ap;
        float4 a1 = *(const float4*)(ap + 4);
        bf16x8 af = pack8(a0, a1);
        #pragma unroll
        for (int ct = 0; ct < 12; ++ct) {
            bf16x8 bf = *(const bf16x8*)(linwt + (size_t)(ct * 16 + l15) * DIN + k0 + kg);
            acc[ct] = __builtin_amdgcn_mfma_f32_16x16x32_bf16(af, bf, acc[ct], 0, 0, 0);
        }
    }

    float asv[12], adv[12];
    #pragma unroll
    for (int ct = 0; ct < 12; ++ct) {
        int c = ct * 16 + l15;
        asv[ct] = att_src[c]; adv[ct] = att_dst[c];
    }

    int rbase = nb + w * 16 + (lane >> 4) * 4;
    #pragma unroll
    for (int j = 0; j < 4; ++j) {
        int r = rbase + j;
        bool ok = r < N;
        float ps0 = 0.f, ps1 = 0.f, ps2 = 0.f, pd0 = 0.f, pd1 = 0.f, pd2 = 0.f;
        #pragma unroll
        for (int ct = 0; ct < 12; ++ct) {
            float v = acc[ct][j];
            float s = v * asv[ct], d = v * adv[ct];
            if (ct < 4)      { ps0 += s; pd0 += d; }
            else if (ct < 8) { ps1 += s; pd1 += d; }
            else             { ps2 += s; pd2 += d; }
        }
        if (ok) {
            unsigned* row32 = (unsigned*)(xsb + (size_t)r * HC);
            #pragma unroll
            for (int ct = 0; ct < 4; ++ct) {
                int c = ct * 16 + l15;
                row32[c] = (unsigned)f2bf(acc[ct][j]) | ((unsigned)f2bf(acc[ct + 4][j]) << 16);
                xsb[(size_t)r * HC + 128 + c] = f2bf(acc[ct + 8][j]);
            }
        }
        #pragma unroll
        for (int o = 1; o < 16; o <<= 1) {
            ps0 += __shfl_xor(ps0, o, 64); pd0 += __shfl_xor(pd0, o, 64);
            ps1 += __shfl_xor(ps1, o, 64); pd1 += __shfl_xor(pd1, o, 64);
            ps2 += __shfl_xor(ps2, o, 64); pd2 += __shfl_xor(pd2, o, 64);
        }
        if (ok && l15 == 0) {
            a_src[r * HH + 0] = ps0 * LOG2E; a_src[r * HH + 1] = ps1 * LOG2E;
            a_src[r * HH + 2] = ps2 * LOG2E;
            a_dst[r * HH + 0] = pd0 * LOG2E; a_dst[r * HH + 1] = pd1 * LOG2E;
            a_dst[r * HH + 2] = pd2 * LOG2E;
        }
    }
}

// ---------- payload fill (CSR order), 16B/edge, a_dst FOLDED IN ----------
__global__ __launch_bounds__(256) void k_fill(const float* __restrict__ ea,
                                              const int* __restrict__ ei,
                                              const float* __restrict__ a_src,
                                              const float* __restrict__ a_dst,
                                              const float* __restrict__ we,
                                              int* __restrict__ cursor,
                                              uint4* __restrict__ payload, int E) {
    int e = blockIdx.x * blockDim.x + threadIdx.x;
    if (e >= E) return;
    int s = ei[e], d = ei[E + e];
    int pos = atomicAdd(&cursor[d], 1);                  // issue early; hide RMW latency
    float attr[ED];
    #pragma unroll
    for (int j = 0; j < ED; ++j) attr[j] = ea[(size_t)e * ED + j];
    float aeh[HH], lp[HH];
    #pragma unroll
    for (int h = 0; h < HH; ++h) {
        float a = 0.f;
        #pragma unroll
        for (int j = 0; j < ED; ++j) a += attr[j] * we[j * HH + h];   // we pre-scaled
        aeh[h] = a;
        lp[h] = a_src[s * HH + h] + a_dst[d * HH + h] + a;             // all pre-scaled
    }
    uint4 pk;
    pk.x = (unsigned)f2bf(lp[0])  | ((unsigned)f2bf(lp[1])  << 16);
    pk.y = (unsigned)f2bf(lp[2])  | ((unsigned)f2bf(aeh[0]) << 16);
    pk.z = (unsigned)f2bf(aeh[1]) | ((unsigned)f2bf(aeh[2]) << 16);
    pk.w = (unsigned)s;
    payload[pos] = pk;
}

// ---------- FUSED: per-dst softmax+gather (pipelined 4-node loop) -> MLP -> out ----------
__global__ __launch_bounds__(256) void k_gatmlp(const unsigned short* __restrict__ xsb,
                                                const float* __restrict__ a_src,
                                                const float* __restrict__ a_dst,
                                                const int* __restrict__ off,
                                                const int* __restrict__ icnt,
                                                const uint4* __restrict__ payload,
                                                const float* __restrict__ x,
                                                const unsigned short* __restrict__ w1t,
                                                const unsigned short* __restrict__ w2t,
                                                const float* __restrict__ b1p,
                                                const float* __restrict__ g1,
                                                const float* __restrict__ be1,
                                                const float* __restrict__ b2,
                                                const float* __restrict__ g2,
                                                const float* __restrict__ be2,
                                                float* __restrict__ out, int N) {
    __shared__ float4 wbuf[4][64];                 // 4 KB
    __shared__ unsigned short OA[16 * OAP];        // 6.25 KB, padded stride
    __shared__ unsigned short H1s[16 * 72];        // 2.25 KB
    __shared__ float red[2][4][16];                // 512 B
    int lane = threadIdx.x & 63;
    int wid  = threadIdx.x >> 6;
    const unsigned* xs32 = (const unsigned*)xsb;
    unsigned c128ml = 128u - (unsigned)lane;
    int nb16 = blockIdx.x * 16;
    int n0 = nb16 + wid * 4;

    // ---- pipeline prologue: node 0's descriptor + first payload chunk ----
    int begC = 0, degC = 0;
    if (n0 < N) { begC = off[n0]; degC = icnt[n0]; }
    uint4 pC; pC.x = 0; pC.y = 0; pC.z = 0; pC.w = 0;
    if (lane < degC) pC = payload[begC + lane];

    // ======== gather phase: 4 nodes, software-pipelined ========
    #pragma unroll 1
    for (int t = 0; t < 4; ++t) {
        int row = wid * 4 + t;
        int n = n0 + t;
        // issue next node's descriptor loads first (resolve under phase A)
        int begNx = 0, degNx = 0;
        if (t < 3) {
            int nn = n + 1;
            if (nn < N) { begNx = off[nn]; degNx = icnt[nn]; }
        }
        int beg = begC, deg = degC;
        uint4 p0 = pC;

        if (n < N) {
            float pden0 = 0.f, pden1 = 0.f, pden2 = 0.f;
            float pae0 = 0.f, pae1 = 0.f, pae2 = 0.f;
            float a0A = 0.f, a1A = 0.f, a2A = 0.f;
            float a0B = 0.f, a1B = 0.f, a2B = 0.f;
            float a0C = 0.f, a1C = 0.f, a2C = 0.f;

            // ---- chunk 0 (peeled, payload already in p0) ----
            {
                int cn = min(deg, 64);
                float w0 = 0.f, w1 = 0.f, w2 = 0.f;
                int src = 0;
                if (lane < cn) {
                    w0 = exp2f(leaky(bf_lo(p0.x)));
                    w1 = exp2f(leaky(bf_hi(p0.x)));
                    w2 = exp2f(leaky(bf_lo(p0.y)));
                    pae0 += bf_hi(p0.y);
                    pae1 += bf_lo(p0.z);
                    pae2 += bf_hi(p0.z);
                    pden0 += w0; pden1 += w1; pden2 += w2;
                    src = (int)p0.w;
                }
                wbuf[wid][lane] = make_float4(w0, w1, w2, __int_as_float(src));
                // issue next node's payload prefetch (resolves under phase B)
                if (t < 3) {
                    pC.x = 0; pC.y = 0; pC.z = 0; pC.w = 0;
                    if (lane < degNx) pC = payload[begNx + lane];
                }
                // phase B: 3-wide unroll
                int i = 0;
                for (; i + 3 <= cn; i += 3) {
                    float4 ta = wbuf[wid][i];
                    float4 tb = wbuf[wid][i + 1];
                    float4 tc = wbuf[wid][i + 2];
                    unsigned ia = __umul24((unsigned)__float_as_int(ta.w), 96u) + lane;
                    unsigned ib = __umul24((unsigned)__float_as_int(tb.w), 96u) + lane;
                    unsigned ic = __umul24((unsigned)__float_as_int(tc.w), 96u) + lane;
                    unsigned va = xs32[ia];
                    unsigned vb = xs32[ib];
                    unsigned vc = xs32[ic];
                    float xa2 = bf2f(xsb[(ia << 1) + c128ml]);
                    float xb2 = bf2f(xsb[(ib << 1) + c128ml]);
                    float xc2 = bf2f(xsb[(ic << 1) + c128ml]);
                    a0A += ta.x * bf_lo(va); a1A += ta.y * bf_hi(va); a2A += ta.z * xa2;
                    a0B += tb.x * bf_lo(vb); a1B += tb.y * bf_hi(vb); a2B += tb.z * xb2;
                    a0C += tc.x * bf_lo(vc); a1C += tc.y * bf_hi(vc); a2C += tc.z * xc2;
                }
                for (; i < cn; ++i) {
                    float4 ta = wbuf[wid][i];
                    unsigned ia = __umul24((unsigned)__float_as_int(ta.w), 96u) + lane;
                    unsigned va = xs32[ia];
                    a0A += ta.x * bf_lo(va);
                    a1A += ta.y * bf_hi(va);
                    a2A += ta.z * bf2f(xsb[(ia << 1) + c128ml]);
                }
            }
            // ---- remaining chunks (rare: deg > 64) ----
            for (int c0 = 64; c0 < deg; c0 += 64) {
                int cn = min(deg - c0, 64);
                float w0 = 0.f, w1 = 0.f, w2 = 0.f;
                int src = 0;
                if (lane < cn) {
                    uint4 p = payload[beg + c0 + lane];
                    w0 = exp2f(leaky(bf_lo(p.x)));
                    w1 = exp2f(leaky(bf_hi(p.x)));
                    w2 = exp2f(leaky(bf_lo(p.y)));
                    pae0 += bf_hi(p.y);
                    pae1 += bf_lo(p.z);
                    pae2 += bf_hi(p.z);
                    pden0 += w0; pden1 += w1; pden2 += w2;
                    src = (int)p.w;
                }
                wbuf[wid][lane] = make_float4(w0, w1, w2, __int_as_float(src));
                int i = 0;
                for (; i + 3 <= cn; i += 3) {
                    float4 ta = wbuf[wid][i];
                    float4 tb = wbuf[wid][i + 1];
                    float4 tc = wbuf[wid][i + 2];
                    unsigned ia = __umul24((unsigned)__float_as_int(ta.w), 96u) + lane;
                    unsigned ib = __umul24((unsigned)__float_as_int(tb.w), 96u) + lane;
                    unsigned ic = __umul24((unsigned)__float_as_int(tc.w), 96u) + lane;
                    unsigned va = xs32[ia];
                    unsigned vb = xs32[ib];
                    unsigned vc = xs32[ic];
                    float xa2 = bf2f(xsb[(ia << 1) + c128ml]);
                    float xb2 = bf2f(xsb[(ib << 1) + c128ml]);
                    float xc2 = bf2f(xsb[(ic << 1) + c128ml]);
                    a0A += ta.x * bf_lo(va); a1A += ta.y * bf_hi(va); a2A += ta.z * xa2;
                    a0B += tb.x * bf_lo(vb); a1B += tb.y * bf_hi(vb); a2B += tb.z * xb2;
                    a0C += tc.x * bf_lo(vc); a1C += tc.y * bf_hi(vc); a2C += tc.z * xc2;
                }
                for (; i < cn; ++i) {
                    float4 ta = wbuf[wid][i];
                    unsigned ia = __umul24((unsigned)__float_as_int(ta.w), 96u) + lane;
                    unsigned va = xs32[ia];
                    a0A += ta.x * bf_lo(va);
                    a1A += ta.y * bf_hi(va);
                    a2A += ta.z * bf2f(xsb[(ia << 1) + c128ml]);
                }
            }

            #pragma unroll
            for (int o = 32; o; o >>= 1) {
                pden0 += __shfl_xor(pden0, o, 64);
                pden1 += __shfl_xor(pden1, o, 64);
                pden2 += __shfl_xor(pden2, o, 64);
                pae0  += __shfl_xor(pae0, o, 64);
                pae1  += __shfl_xor(pae1, o, 64);
                pae2  += __shfl_xor(pae2, o, 64);
            }

            float dc = fmaxf((float)deg, 1.0f);
            float inv_dc = __builtin_amdgcn_rcpf(dc);
            float sl0 = leaky(a_src[n * HH + 0] + a_dst[n * HH + 0] + pae0 * inv_dc);
            float sl1 = leaky(a_src[n * HH + 1] + a_dst[n * HH + 1] + pae1 * inv_dc);
            float sl2 = leaky(a_src[n * HH + 2] + a_dst[n * HH + 2] + pae2 * inv_dc);
            float e0 = exp2f(sl0), e1 = exp2f(sl1), e2 = exp2f(sl2);
            unsigned ian = __umul24((unsigned)n, 96u) + lane;
            unsigned van = xs32[ian];
            float xn2 = bf2f(xsb[(ian << 1) + c128ml]);
            float r0 = __builtin_amdgcn_rcpf(pden0 + e0);
            float r1 = __builtin_amdgcn_rcpf(pden1 + e1);
            float r2 = __builtin_amdgcn_rcpf(pden2 + e2);
            OA[row * OAP +       lane] = f2bf((a0A + a0B + a0C + e0 * bf_lo(van)) * r0);
            OA[row * OAP +  64 + lane] = f2bf((a1A + a1B + a1C + e1 * bf_hi(van)) * r1);
            OA[row * OAP + 128 + lane] = f2bf((a2A + a2B + a2C + e2 * xn2) * r2);
        } else {
            // still perform pipeline prefetch handoff consistency (no-op loads)
            if (t < 3) { pC.x = 0; pC.y = 0; pC.z = 0; pC.w = 0; }
            OA[row * OAP +       lane] = 0;
            OA[row * OAP +  64 + lane] = 0;
            OA[row * OAP + 128 + lane] = 0;
        }
        begC = begNx; degC = degNx;
    }
    __syncthreads();

    // ======== MLP phase: wave wid owns output cols wid*16..wid*16+15 ========
    int l15 = lane & 15, kg = (lane >> 4) * 8;
    int col = wid * 16 + l15;
    float cb1 = b1p[col], cg1 = g1[col], cbe1 = be1[col];
    float cb2 = b2[col],  cg2 = g2[col], cbe2 = be2[col];

    // GEMM1: [16 x 192] @ [192 x 16(cols of this wave)]
    f32x4 acc = (f32x4){0.f, 0.f, 0.f, 0.f};
    #pragma unroll
    for (int k0 = 0; k0 < HC; k0 += 32) {
        bf16x8 af = *(const bf16x8*)&OA[l15 * OAP + k0 + kg];
        bf16x8 bf = *(const bf16x8*)(w1t + (size_t)col * HC + k0 + kg);
        acc = __builtin_amdgcn_mfma_f32_16x16x32_bf16(af, bf, acc, 0, 0, 0);
    }

    int rj0 = (lane >> 4) * 4;
    float y[4], h1v[4];
    #pragma unroll
    for (int j = 0; j < 4; ++j) {
        int r = min(nb16 + rj0 + j, N - 1);
        y[j] = acc[j] + cb1 + x[(size_t)r * DIN + col];
        float s = y[j], q = y[j] * y[j];
        #pragma unroll
        for (int o = 1; o < 16; o <<= 1) {
            s += __shfl_xor(s, o, 64);
            q += __shfl_xor(q, o, 64);
        }
        if (l15 == 0) { red[0][wid][rj0 + j] = s; red[1][wid][rj0 + j] = q; }
    }
    __syncthreads();
    #pragma unroll
    for (int j = 0; j < 4; ++j) {
        int rj = rj0 + j;
        float s = red[0][0][rj] + red[0][1][rj] + red[0][2][rj] + red[0][3][rj];
        float q = red[1][0][rj] + red[1][1][rj] + red[1][2][rj] + red[1][3][rj];
        float m = s * (1.0f / CC);
        float var = q * (1.0f / CC) - m * m;
        float inv = rsqrtf(var + LN_EPS);
        float h = (y[j] - m) * inv * cg1 + cbe1;
        h1v[j] = h;
        H1s[rj * 72 + col] = f2bf(h);
    }
    __syncthreads();

    // GEMM2: [16 x 64] @ [64 x 16]
    f32x4 acc2 = (f32x4){0.f, 0.f, 0.f, 0.f};
    #pragma unroll
    for (int k0 = 0; k0 < CC; k0 += 32) {
        bf16x8 af = *(const bf16x8*)&H1s[l15 * 72 + k0 + kg];
        bf16x8 bf = *(const bf16x8*)(w2t + (size_t)col * CC + k0 + kg);
        acc2 = __builtin_amdgcn_mfma_f32_16x16x32_bf16(af, bf, acc2, 0, 0, 0);
    }

    float z[4];
    #pragma unroll
    for (int j = 0; j < 4; ++j) {
        z[j] = acc2[j] + cb2 + h1v[j];
        float s = z[j], q = z[j] * z[j];
        #pragma unroll
        for (int o = 1; o < 16; o <<= 1) {
            s += __shfl_xor(s, o, 64);
            q += __shfl_xor(q, o, 64);
        }
        if (l15 == 0) { red[0][wid][rj0 + j] = s; red[1][wid][rj0 + j] = q; }
    }
    __syncthreads();
    #pragma unroll
    for (int j = 0; j < 4; ++j) {
        int rj = rj0 + j;
        float s = red[0][0][rj] + red[0][1][rj] + red[0][2][rj] + red[0][3][rj];
        float q = red[1][0][rj] + red[1][1][rj] + red[1][2][rj] + red[1][3][rj];
        float m = s * (1.0f / CC);
        float var = q * (1.0f / CC) - m * m;
        float inv = rsqrtf(var + LN_EPS);
        int r = nb16 + rj;
        if (r < N)
            out[(size_t)r * CC + col] = (z[j] - m) * inv * cg2 + cbe2;
    }
}

extern "C" void kernel_launch(void* const* d_in, const int* in_sizes, int n_in,
                              void* d_out, int out_size, void* d_ws, size_t ws_size,
                              hipStream_t stream) {
    const float* x          = (const float*)d_in[0];
    const float* edge_attr  = (const float*)d_in[1];
    const float* lin_w      = (const float*)d_in[2];
    const float* att_src    = (const float*)d_in[3];
    const float* att_dst    = (const float*)d_in[4];
    const float* lin_edge_w = (const float*)d_in[5];
    const float* att_edge   = (const float*)d_in[6];
    const float* gat_bias   = (const float*)d_in[7];
    const float* w1         = (const float*)d_in[8];
    const float* b1         = (const float*)d_in[9];
    const float* ln1_g      = (const float*)d_in[10];
    const float* ln1_b      = (const float*)d_in[11];
    const float* w2         = (const float*)d_in[12];
    const float* b2         = (const float*)d_in[13];
    const float* ln2_g      = (const float*)d_in[14];
    const float* ln2_b      = (const float*)d_in[15];
    const int*   ei         = (const int*)d_in[16];
    float* out = (float*)d_out;

    const int N = in_sizes[0] / DIN;
    const int E = in_sizes[1] / ED;
    const int nb_scan = (N + 255) / 256;
    const int nbx = (N + 63) / 64;

    char* ws = (char*)d_ws;
    size_t off_b = 0;
    auto alloc = [&](size_t bytes) {
        size_t o = off_b;
        off_b = (off_b + bytes + 255) & ~(size_t)255;
        return o;
    };
    // zeroed region first (single memset)
    int* icnt = (int*)(ws + alloc((size_t)N * 4));
    int* gtot = (int*)(ws + alloc(4));
    size_t zero_bytes = off_b;
    // fully-overwritten region
    unsigned short* xsb = (unsigned short*)(ws + alloc((size_t)N * HC * 2));
    float*  a_srcb  = (float*)(ws + alloc((size_t)N * HH * 4));
    float*  a_dstb  = (float*)(ws + alloc((size_t)N * HH * 4));
    int*    offb    = (int*)(ws + alloc((size_t)N * 4));
    int*    cursor  = (int*)(ws + alloc((size_t)N * 4));
    uint4*  payload = (uint4*)(ws + alloc((size_t)E * 16));
    unsigned short* linwt = (unsigned short*)(ws + alloc((size_t)HC * DIN * 2));
    unsigned short* w1t   = (unsigned short*)(ws + alloc((size_t)DIN * HC * 2));
    unsigned short* w2t   = (unsigned short*)(ws + alloc((size_t)CC * CC * 2));
    float* b1p = (float*)(ws + alloc((size_t)CC * 4));
    float* we  = (float*)(ws + alloc((size_t)ED * HH * 4));
    (void)ws_size; (void)n_in; (void)out_size;

    hipMemsetAsync(d_ws, 0, zero_bytes, stream);

    k_prep_cnt<<<PREP_BLOCKS + 1 + (E + 255) / 256, 256, 0, stream>>>(
        lin_w, w1, w2, b1, gat_bias, lin_edge_w, att_edge,
        linwt, w1t, w2t, b1p, we, ei, icnt, E);
    k_xs<<<nbx + nb_scan, 256, 0, stream>>>(x, linwt, att_src, att_dst, xsb,
                                            a_srcb, a_dstb, icnt, gtot, offb, cursor,
                                            N, nbx);
    k_fill<<<(E + 255) / 256, 256, 0, stream>>>(edge_attr, ei, a_srcb, a_dstb, we, cursor,
                                                payload, E);
    k_gatmlp<<<(N + 15) / 16, 256, 0, stream>>>(xsb, a_srcb, a_dstb, offb, icnt, payload,
                                                x, w1t, w2t, b1p, ln1_g, ln1_b,
                                                b2, ln2_g, ln2_b, out, N);
}